// Round 16
// baseline (186.504 us; speedup 1.0000x reference)
//
#include <hip/hip_runtime.h>

#define NN 100000
#define NE 1600000
#define HID 64
#define BK 128                // nodes per bucket
#define NBUK ((NN + BK - 1) / BK)           // 782 buckets
#define SRCBITS 17
#define SRCMASK 0x1FFFF
#define EBLK 2048             // edges per histogram/fill block
#define GE2 ((NE + EBLK - 1) / EBLK)        // 782 edge-blocks
#define SCANN (NBUK * GE2)    // 611,524
#define CHUNK 1024
#define NCH ((SCANN + CHUNK - 1) / CHUNK)   // 598 chunks

typedef __attribute__((ext_vector_type(8))) short bf16x8;
typedef __attribute__((ext_vector_type(4))) float f32x4;

__device__ __forceinline__ float bf2f(unsigned short u) {
    return __uint_as_float(((unsigned int)u) << 16);
}
__device__ __forceinline__ unsigned short f2bf(float f) {   // RTNE
    unsigned int x = __float_as_uint(f);
    return (unsigned short)((x + 0x7FFFu + ((x >> 16) & 1u)) >> 16);
}
__device__ __forceinline__ float bflo(unsigned int u) { return __uint_as_float(u << 16); }
__device__ __forceinline__ float bfhi(unsigned int u) { return __uint_as_float(u & 0xFFFF0000u); }

__device__ __forceinline__ int ld_idx(const int* __restrict__ ei, int off, int is64) {
    return is64 ? ei[2 * off] : ei[off];
}

// int64 edges have all-zero odd int32 words (values < 2^31). Wave-0 ballot.
__device__ __forceinline__ int detect_flag(const int* __restrict__ ei, int t, int* sflag) {
    if (t < 64) {
        unsigned long long b = __ballot(ei[2 * t + 1] != 0);
        if (t == 0) *sflag = (b == 0ULL) ? 1 : 0;  // 1 => int64 layout
    }
    __syncthreads();
    return *sflag;
}

// ---- pass A1: per-block bucket histogram (LDS atomics only) ----------------
__global__ void k_histA(const int* __restrict__ ei, int* __restrict__ histG) {
    __shared__ int hist[NBUK];
    __shared__ int sflag;
    int t = threadIdx.x;  // 256
    for (int i = t; i < NBUK; i += 256) hist[i] = 0;
    int f = detect_flag(ei, t, &sflag);   // includes __syncthreads
    int base = blockIdx.x * EBLK;
#pragma unroll
    for (int k = 0; k < EBLK / 256; ++k) {
        int e = base + k * 256 + t;
        if (e < NE) {
            int d = ld_idx(ei, NE + e, f);
            atomicAdd(&hist[d >> 7], 1);
        }
    }
    __syncthreads();
    for (int i = t; i < NBUK; i += 256) histG[i * GE2 + blockIdx.x] = hist[i];
}

// ---- 2-stage scan; chunk-prefix fixup is folded into consumers -------------
__global__ void k_scan1(int* __restrict__ g, int* __restrict__ bsum) {
    __shared__ int s[256];
    int t = threadIdx.x;
    int i4 = blockIdx.x * 256 + t;
    int base = i4 * 4;
    int4 v = make_int4(0, 0, 0, 0);
    if (base + 3 < SCANN) v = ((const int4*)g)[i4];
    else {
        if (base + 0 < SCANN) v.x = g[base + 0];
        if (base + 1 < SCANN) v.y = g[base + 1];
        if (base + 2 < SCANN) v.z = g[base + 2];
        if (base + 3 < SCANN) v.w = g[base + 3];
    }
    int tsum = v.x + v.y + v.z + v.w;
    s[t] = tsum; __syncthreads();
    for (int off = 1; off < 256; off <<= 1) {
        int u = (t >= off) ? s[t - off] : 0;
        __syncthreads();
        s[t] += u;
        __syncthreads();
    }
    int run = s[t] - tsum;
    int4 o;
    o.x = run; run += v.x;
    o.y = run; run += v.y;
    o.z = run; run += v.z;
    o.w = run;
    if (base + 3 < SCANN) ((int4*)g)[i4] = o;
    else {
        if (base + 0 < SCANN) g[base + 0] = o.x;
        if (base + 1 < SCANN) g[base + 1] = o.y;
        if (base + 2 < SCANN) g[base + 2] = o.z;
        if (base + 3 < SCANN) g[base + 3] = o.w;
    }
    if (t == 255) bsum[blockIdx.x] = s[255];
}

__global__ void k_scan2(int* __restrict__ bsum) {
    __shared__ int s[1024];
    int t = threadIdx.x;  // 1024
    int v = (t < NCH) ? bsum[t] : 0;
    s[t] = v; __syncthreads();
    for (int off = 1; off < 1024; off <<= 1) {
        int u = (t >= off) ? s[t - off] : 0;
        __syncthreads();
        s[t] += u;
        __syncthreads();
    }
    if (t < NCH) bsum[t] = s[t] - v;
}

// ---- pass A2: place packed edges into disjoint per-(block,bucket) ranges ---
__global__ void k_fillA(const int* __restrict__ ei, const int* __restrict__ histS,
                        const int* __restrict__ bsum, unsigned int* __restrict__ bbuf) {
    __shared__ int cur[NBUK];
    __shared__ int sflag;
    int t = threadIdx.x;  // 256
    for (int i = t; i < NBUK; i += 256) {
        int idx = i * GE2 + blockIdx.x;
        cur[i] = histS[idx] + bsum[idx >> 10];   // fold in chunk prefix
    }
    int f = detect_flag(ei, t, &sflag);   // includes __syncthreads
    int base = blockIdx.x * EBLK;
#pragma unroll
    for (int k = 0; k < EBLK / 256; ++k) {
        int e = base + k * 256 + t;
        if (e < NE) {
            int s = ld_idx(ei, e, f);
            int d = ld_idx(ei, NE + e, f);
            int p = atomicAdd(&cur[d >> 7], 1);   // LDS atomic
            bbuf[p] = ((unsigned int)(d & 127) << SRCBITS) | (unsigned int)s;
        }
    }
}

// ---- pass B: per-bucket 128-slot sort -> cnt/offs/dinv/xs + csr ------------
__global__ void k_passB(const unsigned int* __restrict__ bbuf, const int* __restrict__ histS,
                        const int* __restrict__ bsum, const float* __restrict__ x,
                        int* __restrict__ cnt, int* __restrict__ offs,
                        float* __restrict__ dinv, float* __restrict__ xs,
                        int* __restrict__ csr) {
    __shared__ int hist[BK];
    __shared__ int scn[BK];
    __shared__ int cur[BK];
    int t = threadIdx.x;  // 256
    int b = blockIdx.x;
    int i0 = b * GE2;
    int base = histS[i0] + bsum[i0 >> 10];
    int next = (b == NBUK - 1) ? NE : (histS[i0 + GE2] + bsum[(i0 + GE2) >> 10]);
    int sz = next - base;
    const unsigned int* buf = bbuf + base;
    if (t < BK) hist[t] = 0;
    __syncthreads();
    for (int e = t; e < sz; e += 256)
        atomicAdd(&hist[buf[e] >> SRCBITS], 1);
    __syncthreads();
    int deg = (t < BK) ? hist[t] : 0;
    if (t < BK) scn[t] = deg;
    __syncthreads();
    for (int off = 1; off < BK; off <<= 1) {
        int u = (t >= off && t < BK) ? scn[t - off] : 0;
        __syncthreads();
        if (t < BK) scn[t] += u;
        __syncthreads();
    }
    int node = b * BK + t;
    if (t < BK) {
        int myoff = base + scn[t] - deg;
        cur[t] = myoff;
        if (node < NN) {
            cnt[node]  = deg;
            offs[node] = myoff;
            float d = 1.0f / sqrtf((float)(deg + 1));
            dinv[node] = d;
            float4 xv = ((const float4*)x)[node];
            float4 o; o.x = d * xv.x; o.y = d * xv.y; o.z = d * xv.z; o.w = d * xv.w;
            ((float4*)xs)[node] = o;
        }
    }
    __syncthreads();
    for (int e = t; e < sz; e += 256) {
        unsigned int u = buf[e];
        int p = atomicAdd(&cur[u >> SRCBITS], 1);
        csr[p] = (int)(u & SRCMASK);
    }
}

// ---- fused: layer-1 aggregate (4 thr/node, 4-deep ILP) + h1 + MFMA ---------
// 64 nodes/block, 256 threads. agg = dinv*(sum_nbr xs[s] + xs[self]).
// mfma_f32_16x16x32_bf16: A[m=lane&15][k=quad*8+j]; D col=lane&15, row=quad*4+reg.
__global__ void k_mm2(const float* __restrict__ xs, const int* __restrict__ cnt,
                      const int* __restrict__ offs, const int* __restrict__ csr,
                      const float* __restrict__ dinv,
                      const float* __restrict__ W1, const float* __restrict__ b1,
                      const float* __restrict__ W2, unsigned short* __restrict__ hs) {
    __shared__ unsigned short h1b[64 * 72];   // [localNode][k], bf16, pad 72
    __shared__ unsigned short w2t[64 * 72];   // [n][k], bf16 (W2 transposed)
    __shared__ float4 sPart[256];             // per-(part,node) partial sums
    __shared__ float4 sAgg[64];
    __shared__ float4 sXs[64];
    __shared__ float sW1[256];
    __shared__ float sb1[64];
    __shared__ float sdv[64];
    __shared__ int scnt[64];
    __shared__ int soff[64];
    int t = threadIdx.x;  // 256
    int base = blockIdx.x * 64;
    if (t < 64) {
        int g = base + t;
        bool ok = (g < NN);
        scnt[t] = ok ? cnt[g] : 0;
        soff[t] = ok ? offs[g] : 0;
        sdv[t]  = ok ? dinv[g] : 0.f;
        sXs[t]  = ok ? ((const float4*)xs)[g] : make_float4(0.f, 0.f, 0.f, 0.f);
        sb1[t]  = b1[t];
    }
    sW1[t] = W1[t];
    for (int i = t; i < 4096; i += 256) {     // W2 [k][n] fp32 -> w2t [n][k] bf16
        int k = i >> 6, n = i & 63;
        w2t[n * 72 + k] = f2bf(W2[i]);
    }
    if (blockIdx.x == 0 && t >= 128 && t < 192) hs[NN * 64 + (t - 128)] = 0;  // sentinel row
    __syncthreads();
    // aggregation: node_l = t&63, part = t>>6 handles j = part, part+4, ...
    {
        int node_l = t & 63, part = t >> 6;
        int n = scnt[node_l], b0 = soff[node_l];
        float4 s = make_float4(0.f, 0.f, 0.f, 0.f);
        int j = part;
        for (; j + 12 < n; j += 16) {         // 4 independent loads in flight
            int s0 = csr[b0 + j],     s1 = csr[b0 + j + 4];
            int s2 = csr[b0 + j + 8], s3 = csr[b0 + j + 12];
            float4 v0 = ((const float4*)xs)[s0];
            float4 v1 = ((const float4*)xs)[s1];
            float4 v2 = ((const float4*)xs)[s2];
            float4 v3 = ((const float4*)xs)[s3];
            s.x += (v0.x + v1.x) + (v2.x + v3.x);
            s.y += (v0.y + v1.y) + (v2.y + v3.y);
            s.z += (v0.z + v1.z) + (v2.z + v3.z);
            s.w += (v0.w + v1.w) + (v2.w + v3.w);
        }
        for (; j < n; j += 4) {
            int s0 = csr[b0 + j];
            float4 v = ((const float4*)xs)[s0];
            s.x += v.x; s.y += v.y; s.z += v.z; s.w += v.w;
        }
        sPart[t] = s;
    }
    __syncthreads();
    if (t < 64) {
        float4 a = sPart[t], b = sPart[t + 64], c = sPart[t + 128], d = sPart[t + 192];
        float4 xi = sXs[t];
        float dn = sdv[t];
        float4 o;
        o.x = dn * (a.x + b.x + c.x + d.x + xi.x);
        o.y = dn * (a.y + b.y + c.y + d.y + xi.y);
        o.z = dn * (a.z + b.z + c.z + d.z + xi.z);
        o.w = dn * (a.w + b.w + c.w + d.w + xi.w);
        sAgg[t] = o;
    }
    __syncthreads();
#pragma unroll
    for (int i = 0; i < 16; ++i) {            // h1 = relu(agg@W1+b1), bf16 to LDS
        int e = i * 256 + t;
        int nl = e >> 6, c = e & 63;
        float4 a = sAgg[nl];
        float h = fmaf(a.x, sW1[c], fmaf(a.y, sW1[64 + c],
                  fmaf(a.z, sW1[128 + c], fmaf(a.w, sW1[192 + c], sb1[c]))));
        h1b[nl * 72 + c] = f2bf(fmaxf(h, 0.f));
    }
    __syncthreads();
    int w = t >> 6, lane = t & 63, l15 = lane & 15, quad = lane >> 4;
    bf16x8 a0 = *(const bf16x8*)&h1b[(w * 16 + l15) * 72 + quad * 8];
    bf16x8 a1 = *(const bf16x8*)&h1b[(w * 16 + l15) * 72 + 32 + quad * 8];
    f32x4 acc[4];
#pragma unroll
    for (int nt = 0; nt < 4; ++nt) {
        bf16x8 bb0 = *(const bf16x8*)&w2t[(nt * 16 + l15) * 72 + quad * 8];
        bf16x8 bb1 = *(const bf16x8*)&w2t[(nt * 16 + l15) * 72 + 32 + quad * 8];
        f32x4 c = {0.f, 0.f, 0.f, 0.f};
        c = __builtin_amdgcn_mfma_f32_16x16x32_bf16(a0, bb0, c, 0, 0, 0);
        c = __builtin_amdgcn_mfma_f32_16x16x32_bf16(a1, bb1, c, 0, 0, 0);
        acc[nt] = c;
    }
#pragma unroll
    for (int nt = 0; nt < 4; ++nt) {
#pragma unroll
        for (int r = 0; r < 4; ++r) {
            int localn = w * 16 + quad * 4 + r;
            int g = base + localn;
            if (g < NN) hs[g * 64 + nt * 16 + l15] = f2bf(acc[nt][r] * sdv[localn]);
        }
    }
}

// ---- layer-2 gather + head, fused, quad-row loads (4 in flight). -----------
// Lane c: group qg=c>>4 takes edges j+qg (mod 4); slot ql=c&15 covers cols
// 4ql..4ql+3 (uint2 = 4 bf16). One wave-load = 4 neighbor rows.
__global__ void k_gather_head(const unsigned short* __restrict__ hs, const int* __restrict__ offs,
                              const int* __restrict__ cnt, const int* __restrict__ csr,
                              const float* __restrict__ dinv, const float* __restrict__ b2,
                              const float* __restrict__ Wl, const float* __restrict__ bl,
                              float* __restrict__ out) {
    int t = threadIdx.x;
    int node = blockIdx.x * 4 + (t >> 6);
    int c = t & 63;
    int qg = c >> 4;
    int ql = c & 15;
    int b = offs[node], n = cnt[node];
    const uint2* hrow = (const uint2*)hs;        // 16 uint2 per row
    int myidx = (c < n) ? csr[b + c] : NN;       // NN = zero sentinel row
    int m = n < 64 ? n : 64;
    float4 A = make_float4(0.f, 0.f, 0.f, 0.f);
    float4 B = make_float4(0.f, 0.f, 0.f, 0.f);
    for (int j = 0; j < m; j += 16) {            // 16 edges per iter, 4 loads in flight
        int s0 = __shfl(myidx, j + qg, 64);
        int s1 = __shfl(myidx, j + 4 + qg, 64);
        int s2 = __shfl(myidx, j + 8 + qg, 64);
        int s3 = __shfl(myidx, j + 12 + qg, 64);
        uint2 u0 = hrow[s0 * 16 + ql];
        uint2 u1 = hrow[s1 * 16 + ql];
        uint2 u2 = hrow[s2 * 16 + ql];
        uint2 u3 = hrow[s3 * 16 + ql];
        A.x += bflo(u0.x); A.y += bfhi(u0.x); A.z += bflo(u0.y); A.w += bfhi(u0.y);
        B.x += bflo(u1.x); B.y += bfhi(u1.x); B.z += bflo(u1.y); B.w += bfhi(u1.y);
        A.x += bflo(u2.x); A.y += bfhi(u2.x); A.z += bflo(u2.y); A.w += bfhi(u2.y);
        B.x += bflo(u3.x); B.y += bfhi(u3.x); B.z += bflo(u3.y); B.w += bfhi(u3.y);
    }
    for (int j = 64; j < n; j += 4) {            // rare: deg > 64
        int e = j + qg;
        int s = (e < n) ? csr[b + e] : NN;
        uint2 u = hrow[s * 16 + ql];
        A.x += bflo(u.x); A.y += bfhi(u.x); A.z += bflo(u.y); A.w += bfhi(u.y);
    }
    float4 S;
    S.x = A.x + B.x; S.y = A.y + B.y; S.z = A.z + B.z; S.w = A.w + B.w;
    S.x += __shfl_xor(S.x, 16, 64); S.x += __shfl_xor(S.x, 32, 64);
    S.y += __shfl_xor(S.y, 16, 64); S.y += __shfl_xor(S.y, 32, 64);
    S.z += __shfl_xor(S.z, 16, 64); S.z += __shfl_xor(S.z, 32, 64);
    S.w += __shfl_xor(S.w, 16, 64); S.w += __shfl_xor(S.w, 32, 64);
    uint2 uS = hrow[node * 16 + ql];             // self loop, once
    S.x += bflo(uS.x); S.y += bfhi(uS.x); S.z += bflo(uS.y); S.w += bfhi(uS.y);
    float4 bv = ((const float4*)b2)[ql];
    float4 wv = ((const float4*)Wl)[ql];
    float dn = dinv[node];
    float v = fmaxf(fmaf(dn, S.x, bv.x), 0.f) * wv.x
            + fmaxf(fmaf(dn, S.y, bv.y), 0.f) * wv.y
            + fmaxf(fmaf(dn, S.z, bv.z), 0.f) * wv.z
            + fmaxf(fmaf(dn, S.w, bv.w), 0.f) * wv.w;
#pragma unroll
    for (int off = 8; off; off >>= 1) v += __shfl_down(v, off, 16);
    if (c == 0) out[node] = v + bl[0];
}

extern "C" void kernel_launch(void* const* d_in, const int* in_sizes, int n_in,
                              void* d_out, int out_size, void* d_ws, size_t ws_size,
                              hipStream_t stream) {
    const float* x  = (const float*)d_in[0];
    const int*   ei = (const int*)d_in[1];
    const float* W1 = (const float*)d_in[2];
    const float* b1 = (const float*)d_in[3];
    const float* W2 = (const float*)d_in[4];
    const float* b2 = (const float*)d_in[5];
    const float* Wl = (const float*)d_in[6];
    const float* bl = (const float*)d_in[7];
    float* out = (float*)d_out;

    char* w = (char*)d_ws;
    float* dinv  = (float*)w;                  w += NN * 4;
    int*   cnt   = (int*)w;                    w += NN * 4;
    int*   offs  = (int*)w;                    w += NN * 4;
    int*   csr   = (int*)w;                    w += NE * 4;
    float* xs    = (float*)w;                  w += NN * 4 * 4;
    unsigned short* hs = (unsigned short*)w;   w += (size_t)(NN + 1) * HID * 2;     // 12.8 MB (+sentinel)
    int*   histG = (int*)w;                    w += (size_t)((SCANN + 3) & ~3) * 4; // 2.45 MB
    int*   bsum  = (int*)w;                    w += 1024 * 4;
    unsigned int* bbuf = (unsigned int*)w;     w += (size_t)NE * 4;                 // 6.4 MB

    const int GMM = (NN + 63) / 64;        // 1563

    hipLaunchKernelGGL(k_histA,  dim3(GE2),  dim3(256),  0, stream, ei, histG);
    hipLaunchKernelGGL(k_scan1,  dim3(NCH),  dim3(256),  0, stream, histG, bsum);
    hipLaunchKernelGGL(k_scan2,  dim3(1),    dim3(1024), 0, stream, bsum);
    hipLaunchKernelGGL(k_fillA,  dim3(GE2),  dim3(256),  0, stream, ei, histG, bsum, bbuf);
    hipLaunchKernelGGL(k_passB,  dim3(NBUK), dim3(256),  0, stream,
                       bbuf, histG, bsum, x, cnt, offs, dinv, xs, csr);
    hipLaunchKernelGGL(k_mm2, dim3(GMM), dim3(256), 0, stream,
                       xs, cnt, offs, csr, dinv, W1, b1, W2, hs);
    hipLaunchKernelGGL(k_gather_head, dim3(NN / 4), dim3(256), 0, stream,
                       hs, offs, cnt, csr, dinv, b2, Wl, bl, out);
}

// Round 17
// 174.308 us; speedup vs baseline: 1.0700x; 1.0700x over previous
//
#include <hip/hip_runtime.h>

#define NN 100000
#define NE 1600000
#define HID 64
#define NBUK 391              // buckets of 256 node ids: (NN+255)/256
#define SRCBITS 17
#define SRCMASK 0x1FFFF
#define EBLK 4096             // edges per histogram/fill block
#define GE2 ((NE + EBLK - 1) / EBLK)        // 391 edge-blocks
#define SCANN (NBUK * GE2)    // 152,881
#define CHUNK 1024
#define NCH ((SCANN + CHUNK - 1) / CHUNK)   // 150 chunks

typedef __attribute__((ext_vector_type(8))) short bf16x8;
typedef __attribute__((ext_vector_type(4))) float f32x4;

__device__ __forceinline__ float bf2f(unsigned short u) {
    return __uint_as_float(((unsigned int)u) << 16);
}
__device__ __forceinline__ unsigned short f2bf(float f) {   // RTNE
    unsigned int x = __float_as_uint(f);
    return (unsigned short)((x + 0x7FFFu + ((x >> 16) & 1u)) >> 16);
}
__device__ __forceinline__ float bflo(unsigned int u) { return __uint_as_float(u << 16); }
__device__ __forceinline__ float bfhi(unsigned int u) { return __uint_as_float(u & 0xFFFF0000u); }

__device__ __forceinline__ int ld_idx(const int* __restrict__ ei, int off, int is64) {
    return is64 ? ei[2 * off] : ei[off];
}

// int64 edges have all-zero odd int32 words (values < 2^31). Wave-0 ballot.
__device__ __forceinline__ int detect_flag(const int* __restrict__ ei, int t, int* sflag) {
    if (t < 64) {
        unsigned long long b = __ballot(ei[2 * t + 1] != 0);
        if (t == 0) *sflag = (b == 0ULL) ? 1 : 0;  // 1 => int64 layout
    }
    __syncthreads();
    return *sflag;
}

// ---- pass A1: per-block bucket histogram (LDS atomics only) ----------------
__global__ void k_histA(const int* __restrict__ ei, int* __restrict__ histG) {
    __shared__ int hist[NBUK];
    __shared__ int sflag;
    int t = threadIdx.x;  // 256
    for (int i = t; i < NBUK; i += 256) hist[i] = 0;
    int f = detect_flag(ei, t, &sflag);   // includes __syncthreads
    int base = blockIdx.x * EBLK;
#pragma unroll
    for (int k = 0; k < EBLK / 256; ++k) {
        int e = base + k * 256 + t;
        if (e < NE) {
            int d = ld_idx(ei, NE + e, f);
            atomicAdd(&hist[d >> 8], 1);
        }
    }
    __syncthreads();
    for (int i = t; i < NBUK; i += 256) histG[i * GE2 + blockIdx.x] = hist[i];
}

// ---- 2-stage scan; chunk-prefix fixup is folded into consumers -------------
__global__ void k_scan1(int* __restrict__ g, int* __restrict__ bsum) {
    __shared__ int s[256];
    int t = threadIdx.x;
    int i4 = blockIdx.x * 256 + t;
    int base = i4 * 4;
    int4 v = make_int4(0, 0, 0, 0);
    if (base + 3 < SCANN) v = ((const int4*)g)[i4];
    else {
        if (base + 0 < SCANN) v.x = g[base + 0];
        if (base + 1 < SCANN) v.y = g[base + 1];
        if (base + 2 < SCANN) v.z = g[base + 2];
        if (base + 3 < SCANN) v.w = g[base + 3];
    }
    int tsum = v.x + v.y + v.z + v.w;
    s[t] = tsum; __syncthreads();
    for (int off = 1; off < 256; off <<= 1) {
        int u = (t >= off) ? s[t - off] : 0;
        __syncthreads();
        s[t] += u;
        __syncthreads();
    }
    int run = s[t] - tsum;
    int4 o;
    o.x = run; run += v.x;
    o.y = run; run += v.y;
    o.z = run; run += v.z;
    o.w = run;
    if (base + 3 < SCANN) ((int4*)g)[i4] = o;
    else {
        if (base + 0 < SCANN) g[base + 0] = o.x;
        if (base + 1 < SCANN) g[base + 1] = o.y;
        if (base + 2 < SCANN) g[base + 2] = o.z;
        if (base + 3 < SCANN) g[base + 3] = o.w;
    }
    if (t == 255) bsum[blockIdx.x] = s[255];
}

__global__ void k_scan2(int* __restrict__ bsum) {
    __shared__ int s[256];
    int t = threadIdx.x;  // 256
    int v = (t < NCH) ? bsum[t] : 0;
    s[t] = v; __syncthreads();
    for (int off = 1; off < 256; off <<= 1) {
        int u = (t >= off) ? s[t - off] : 0;
        __syncthreads();
        s[t] += u;
        __syncthreads();
    }
    if (t < NCH) bsum[t] = s[t] - v;
}

// ---- pass A2: place packed edges into disjoint per-(block,bucket) ranges ---
__global__ void k_fillA(const int* __restrict__ ei, const int* __restrict__ histS,
                        const int* __restrict__ bsum, unsigned int* __restrict__ bbuf) {
    __shared__ int cur[NBUK];
    __shared__ int sflag;
    int t = threadIdx.x;  // 256
    for (int i = t; i < NBUK; i += 256) {
        int idx = i * GE2 + blockIdx.x;
        cur[i] = histS[idx] + bsum[idx >> 10];   // fold in chunk prefix
    }
    int f = detect_flag(ei, t, &sflag);   // includes __syncthreads
    int base = blockIdx.x * EBLK;
#pragma unroll
    for (int k = 0; k < EBLK / 256; ++k) {
        int e = base + k * 256 + t;
        if (e < NE) {
            int s = ld_idx(ei, e, f);
            int d = ld_idx(ei, NE + e, f);
            int p = atomicAdd(&cur[d >> 8], 1);   // LDS atomic
            bbuf[p] = ((unsigned int)(d & 255) << SRCBITS) | (unsigned int)s;
        }
    }
}

// ---- pass B: per-bucket 256-slot sort -> cnt/offs/dinv/xs + csr ------------
__global__ void k_passB(const unsigned int* __restrict__ bbuf, const int* __restrict__ histS,
                        const int* __restrict__ bsum, const float* __restrict__ x,
                        int* __restrict__ cnt, int* __restrict__ offs,
                        float* __restrict__ dinv, float* __restrict__ xs,
                        int* __restrict__ csr) {
    __shared__ int hist[256];
    __shared__ int scn[256];
    __shared__ int cur[256];
    int t = threadIdx.x;  // 256
    int b = blockIdx.x;
    int i0 = b * GE2;
    int base = histS[i0] + bsum[i0 >> 10];
    int next = (b == NBUK - 1) ? NE : (histS[i0 + GE2] + bsum[(i0 + GE2) >> 10]);
    int sz = next - base;
    const unsigned int* buf = bbuf + base;
    hist[t] = 0;
    __syncthreads();
    for (int e = t; e < sz; e += 256)
        atomicAdd(&hist[buf[e] >> SRCBITS], 1);
    __syncthreads();
    int deg = hist[t];
    scn[t] = deg; __syncthreads();
    for (int off = 1; off < 256; off <<= 1) {
        int u = (t >= off) ? scn[t - off] : 0;
        __syncthreads();
        scn[t] += u;
        __syncthreads();
    }
    int myoff = base + scn[t] - deg;
    int node = b * 256 + t;
    if (node < NN) {
        cnt[node]  = deg;
        offs[node] = myoff;
        float d = 1.0f / sqrtf((float)(deg + 1));
        dinv[node] = d;
        float4 xv = ((const float4*)x)[node];
        float4 o; o.x = d * xv.x; o.y = d * xv.y; o.z = d * xv.z; o.w = d * xv.w;
        ((float4*)xs)[node] = o;
    }
    cur[t] = myoff;
    __syncthreads();
    for (int e = t; e < sz; e += 256) {
        unsigned int u = buf[e];
        int p = atomicAdd(&cur[u >> SRCBITS], 1);
        csr[p] = (int)(u & SRCMASK);
    }
}

// ---- fused: layer-1 aggregate (4 thr/node) + h1 + MFMA h1@W2 -> hs ---------
// 64 nodes/block, 256 threads. agg = dinv*(sum_nbr xs[s] + xs[self]).
// mfma_f32_16x16x32_bf16: A[m=lane&15][k=quad*8+j]; D col=lane&15, row=quad*4+reg.
__global__ void k_mm2(const float* __restrict__ xs, const int* __restrict__ cnt,
                      const int* __restrict__ offs, const int* __restrict__ csr,
                      const float* __restrict__ dinv,
                      const float* __restrict__ W1, const float* __restrict__ b1,
                      const float* __restrict__ W2, unsigned short* __restrict__ hs) {
    __shared__ unsigned short h1b[64 * 72];   // [localNode][k], bf16, pad 72
    __shared__ unsigned short w2t[64 * 72];   // [n][k], bf16 (W2 transposed)
    __shared__ float4 sPart[256];             // per-(part,node) partial sums
    __shared__ float4 sAgg[64];
    __shared__ float4 sXs[64];
    __shared__ float sW1[256];
    __shared__ float sb1[64];
    __shared__ float sdv[64];
    __shared__ int scnt[64];
    __shared__ int soff[64];
    int t = threadIdx.x;  // 256
    int base = blockIdx.x * 64;
    if (t < 64) {
        int g = base + t;
        bool ok = (g < NN);
        scnt[t] = ok ? cnt[g] : 0;
        soff[t] = ok ? offs[g] : 0;
        sdv[t]  = ok ? dinv[g] : 0.f;
        sXs[t]  = ok ? ((const float4*)xs)[g] : make_float4(0.f, 0.f, 0.f, 0.f);
        sb1[t]  = b1[t];
    }
    sW1[t] = W1[t];
    for (int i = t; i < 4096; i += 256) {     // W2 [k][n] fp32 -> w2t [n][k] bf16
        int k = i >> 6, n = i & 63;
        w2t[n * 72 + k] = f2bf(W2[i]);
    }
    if (blockIdx.x == 0 && t >= 128 && t < 192) hs[NN * 64 + (t - 128)] = 0;  // sentinel row
    __syncthreads();
    // aggregation: node_l = t&63, part = t>>6 handles j = part, part+4, ...
    {
        int node_l = t & 63, part = t >> 6;
        int n = scnt[node_l], b0 = soff[node_l];
        float4 s = make_float4(0.f, 0.f, 0.f, 0.f);
        int j = part;
        for (; j + 4 < n; j += 8) {           // 2 independent loads in flight
            int s0 = csr[b0 + j], s1 = csr[b0 + j + 4];
            float4 v0 = ((const float4*)xs)[s0];
            float4 v1 = ((const float4*)xs)[s1];
            s.x += v0.x + v1.x; s.y += v0.y + v1.y;
            s.z += v0.z + v1.z; s.w += v0.w + v1.w;
        }
        for (; j < n; j += 4) {
            int s0 = csr[b0 + j];
            float4 v = ((const float4*)xs)[s0];
            s.x += v.x; s.y += v.y; s.z += v.z; s.w += v.w;
        }
        sPart[t] = s;
    }
    __syncthreads();
    if (t < 64) {
        float4 a = sPart[t], b = sPart[t + 64], c = sPart[t + 128], d = sPart[t + 192];
        float4 xi = sXs[t];
        float dn = sdv[t];
        float4 o;
        o.x = dn * (a.x + b.x + c.x + d.x + xi.x);
        o.y = dn * (a.y + b.y + c.y + d.y + xi.y);
        o.z = dn * (a.z + b.z + c.z + d.z + xi.z);
        o.w = dn * (a.w + b.w + c.w + d.w + xi.w);
        sAgg[t] = o;
    }
    __syncthreads();
#pragma unroll
    for (int i = 0; i < 16; ++i) {            // h1 = relu(agg@W1+b1), bf16 to LDS
        int e = i * 256 + t;
        int nl = e >> 6, c = e & 63;
        float4 a = sAgg[nl];
        float h = fmaf(a.x, sW1[c], fmaf(a.y, sW1[64 + c],
                  fmaf(a.z, sW1[128 + c], fmaf(a.w, sW1[192 + c], sb1[c]))));
        h1b[nl * 72 + c] = f2bf(fmaxf(h, 0.f));
    }
    __syncthreads();
    int w = t >> 6, lane = t & 63, l15 = lane & 15, quad = lane >> 4;
    bf16x8 a0 = *(const bf16x8*)&h1b[(w * 16 + l15) * 72 + quad * 8];
    bf16x8 a1 = *(const bf16x8*)&h1b[(w * 16 + l15) * 72 + 32 + quad * 8];
    f32x4 acc[4];
#pragma unroll
    for (int nt = 0; nt < 4; ++nt) {
        bf16x8 bb0 = *(const bf16x8*)&w2t[(nt * 16 + l15) * 72 + quad * 8];
        bf16x8 bb1 = *(const bf16x8*)&w2t[(nt * 16 + l15) * 72 + 32 + quad * 8];
        f32x4 c = {0.f, 0.f, 0.f, 0.f};
        c = __builtin_amdgcn_mfma_f32_16x16x32_bf16(a0, bb0, c, 0, 0, 0);
        c = __builtin_amdgcn_mfma_f32_16x16x32_bf16(a1, bb1, c, 0, 0, 0);
        acc[nt] = c;
    }
#pragma unroll
    for (int nt = 0; nt < 4; ++nt) {
#pragma unroll
        for (int r = 0; r < 4; ++r) {
            int localn = w * 16 + quad * 4 + r;
            int g = base + localn;
            if (g < NN) hs[g * 64 + nt * 16 + l15] = f2bf(acc[nt][r] * sdv[localn]);
        }
    }
}

// ---- layer-2 gather + head, fused, quad-row loads (4 in flight). -----------
// Lane c: group qg=c>>4 takes edges j+qg (mod 4); slot ql=c&15 covers cols
// 4ql..4ql+3 (uint2 = 4 bf16). One wave-load = 4 neighbor rows.
__global__ void k_gather_head(const unsigned short* __restrict__ hs, const int* __restrict__ offs,
                              const int* __restrict__ cnt, const int* __restrict__ csr,
                              const float* __restrict__ dinv, const float* __restrict__ b2,
                              const float* __restrict__ Wl, const float* __restrict__ bl,
                              float* __restrict__ out) {
    int t = threadIdx.x;
    int node = blockIdx.x * 4 + (t >> 6);
    int c = t & 63;
    int qg = c >> 4;
    int ql = c & 15;
    int b = offs[node], n = cnt[node];
    const uint2* hrow = (const uint2*)hs;        // 16 uint2 per row
    int myidx = (c < n) ? csr[b + c] : NN;       // NN = zero sentinel row
    int m = n < 64 ? n : 64;
    float4 A = make_float4(0.f, 0.f, 0.f, 0.f);
    float4 B = make_float4(0.f, 0.f, 0.f, 0.f);
    for (int j = 0; j < m; j += 16) {            // 16 edges per iter, 4 loads in flight
        int s0 = __shfl(myidx, j + qg, 64);
        int s1 = __shfl(myidx, j + 4 + qg, 64);
        int s2 = __shfl(myidx, j + 8 + qg, 64);
        int s3 = __shfl(myidx, j + 12 + qg, 64);
        uint2 u0 = hrow[s0 * 16 + ql];
        uint2 u1 = hrow[s1 * 16 + ql];
        uint2 u2 = hrow[s2 * 16 + ql];
        uint2 u3 = hrow[s3 * 16 + ql];
        A.x += bflo(u0.x); A.y += bfhi(u0.x); A.z += bflo(u0.y); A.w += bfhi(u0.y);
        B.x += bflo(u1.x); B.y += bfhi(u1.x); B.z += bflo(u1.y); B.w += bfhi(u1.y);
        A.x += bflo(u2.x); A.y += bfhi(u2.x); A.z += bflo(u2.y); A.w += bfhi(u2.y);
        B.x += bflo(u3.x); B.y += bfhi(u3.x); B.z += bflo(u3.y); B.w += bfhi(u3.y);
    }
    for (int j = 64; j < n; j += 4) {            // rare: deg > 64
        int e = j + qg;
        int s = (e < n) ? csr[b + e] : NN;
        uint2 u = hrow[s * 16 + ql];
        A.x += bflo(u.x); A.y += bfhi(u.x); A.z += bflo(u.y); A.w += bfhi(u.y);
    }
    float4 S;
    S.x = A.x + B.x; S.y = A.y + B.y; S.z = A.z + B.z; S.w = A.w + B.w;
    S.x += __shfl_xor(S.x, 16, 64); S.x += __shfl_xor(S.x, 32, 64);
    S.y += __shfl_xor(S.y, 16, 64); S.y += __shfl_xor(S.y, 32, 64);
    S.z += __shfl_xor(S.z, 16, 64); S.z += __shfl_xor(S.z, 32, 64);
    S.w += __shfl_xor(S.w, 16, 64); S.w += __shfl_xor(S.w, 32, 64);
    uint2 uS = hrow[node * 16 + ql];             // self loop, once
    S.x += bflo(uS.x); S.y += bfhi(uS.x); S.z += bflo(uS.y); S.w += bfhi(uS.y);
    float4 bv = ((const float4*)b2)[ql];
    float4 wv = ((const float4*)Wl)[ql];
    float dn = dinv[node];
    float v = fmaxf(fmaf(dn, S.x, bv.x), 0.f) * wv.x
            + fmaxf(fmaf(dn, S.y, bv.y), 0.f) * wv.y
            + fmaxf(fmaf(dn, S.z, bv.z), 0.f) * wv.z
            + fmaxf(fmaf(dn, S.w, bv.w), 0.f) * wv.w;
#pragma unroll
    for (int off = 8; off; off >>= 1) v += __shfl_down(v, off, 16);
    if (c == 0) out[node] = v + bl[0];
}

extern "C" void kernel_launch(void* const* d_in, const int* in_sizes, int n_in,
                              void* d_out, int out_size, void* d_ws, size_t ws_size,
                              hipStream_t stream) {
    const float* x  = (const float*)d_in[0];
    const int*   ei = (const int*)d_in[1];
    const float* W1 = (const float*)d_in[2];
    const float* b1 = (const float*)d_in[3];
    const float* W2 = (const float*)d_in[4];
    const float* b2 = (const float*)d_in[5];
    const float* Wl = (const float*)d_in[6];
    const float* bl = (const float*)d_in[7];
    float* out = (float*)d_out;

    char* w = (char*)d_ws;
    float* dinv  = (float*)w;                  w += NN * 4;
    int*   cnt   = (int*)w;                    w += NN * 4;
    int*   offs  = (int*)w;                    w += NN * 4;
    int*   csr   = (int*)w;                    w += NE * 4;
    float* xs    = (float*)w;                  w += NN * 4 * 4;
    unsigned short* hs = (unsigned short*)w;   w += (size_t)(NN + 1) * HID * 2;     // 12.8 MB (+sentinel)
    int*   histG = (int*)w;                    w += (size_t)((SCANN + 3) & ~3) * 4; // 612 KB
    int*   bsum  = (int*)w;                    w += 256 * 4;
    unsigned int* bbuf = (unsigned int*)w;     w += (size_t)NE * 4;                 // 6.4 MB

    const int GMM = (NN + 63) / 64;        // 1563

    hipLaunchKernelGGL(k_histA,  dim3(GE2),  dim3(256), 0, stream, ei, histG);
    hipLaunchKernelGGL(k_scan1,  dim3(NCH),  dim3(256), 0, stream, histG, bsum);
    hipLaunchKernelGGL(k_scan2,  dim3(1),    dim3(256), 0, stream, bsum);
    hipLaunchKernelGGL(k_fillA,  dim3(GE2),  dim3(256), 0, stream, ei, histG, bsum, bbuf);
    hipLaunchKernelGGL(k_passB,  dim3(NBUK), dim3(256), 0, stream,
                       bbuf, histG, bsum, x, cnt, offs, dinv, xs, csr);
    hipLaunchKernelGGL(k_mm2, dim3(GMM), dim3(256), 0, stream,
                       xs, cnt, offs, csr, dinv, W1, b1, W2, hs);
    hipLaunchKernelGGL(k_gather_head, dim3(NN / 4), dim3(256), 0, stream,
                       hs, offs, cnt, csr, dinv, b2, Wl, bl, out);
}

// Round 18
// 167.790 us; speedup vs baseline: 1.1115x; 1.0388x over previous
//
#include <hip/hip_runtime.h>

#define NN 100000
#define NE 1600000
#define HID 64
#define NBUK 391              // buckets of 256 node ids: (NN+255)/256
#define SRCBITS 17
#define SRCMASK 0x1FFFF
#define EBLK 4096             // edges per histogram/fill block
#define GE2 ((NE + EBLK - 1) / EBLK)        // 391 edge-blocks
#define SCANN (NBUK * GE2)    // 152,881
#define CHUNK 1024
#define NCH ((SCANN + CHUNK - 1) / CHUNK)   // 150 chunks

typedef __attribute__((ext_vector_type(8))) short bf16x8;
typedef __attribute__((ext_vector_type(4))) float f32x4;

__device__ __forceinline__ float bf2f(unsigned short u) {
    return __uint_as_float(((unsigned int)u) << 16);
}
__device__ __forceinline__ unsigned short f2bf(float f) {   // RTNE
    unsigned int x = __float_as_uint(f);
    return (unsigned short)((x + 0x7FFFu + ((x >> 16) & 1u)) >> 16);
}
__device__ __forceinline__ float bflo(unsigned int u) { return __uint_as_float(u << 16); }
__device__ __forceinline__ float bfhi(unsigned int u) { return __uint_as_float(u & 0xFFFF0000u); }

// int64 edges have all-zero odd int32 words (values < 2^31). Wave-0 ballot.
__device__ __forceinline__ int detect_flag(const int* __restrict__ ei, int t, int* sflag) {
    if (t < 64) {
        unsigned long long b = __ballot(ei[2 * t + 1] != 0);
        if (t == 0) *sflag = (b == 0ULL) ? 1 : 0;  // 1 => int64 layout
    }
    __syncthreads();
    return *sflag;
}

// ---- pass A1: per-block bucket histogram, int4-vectorized edge stream ------
__global__ void k_histA(const int* __restrict__ ei, int* __restrict__ histG) {
    __shared__ int hist[NBUK];
    __shared__ int sflag;
    int t = threadIdx.x;  // 256
    for (int i = t; i < NBUK; i += 256) hist[i] = 0;
    int f = detect_flag(ei, t, &sflag);   // includes __syncthreads
    int base = blockIdx.x * EBLK;
    if (f) {                               // int64: int4 = 2 edges' dst words
        const int4* pd = (const int4*)(ei + 2 * (size_t)NE);
#pragma unroll
        for (int k = 0; k < EBLK / 512; ++k) {
            int e = base + k * 512 + t * 2;
            if (e < NE) {
                int4 v = pd[e >> 1];
                atomicAdd(&hist[v.x >> 8], 1);
                atomicAdd(&hist[v.z >> 8], 1);   // e+1 < NE (NE even, e even)
            }
        }
    } else {                               // int32: int4 = 4 dsts
        const int4* pd = (const int4*)(ei + NE);
#pragma unroll
        for (int k = 0; k < EBLK / 1024; ++k) {
            int e = base + k * 1024 + t * 4;
            if (e < NE) {                  // NE % 4 == 0 -> whole quad valid
                int4 v = pd[e >> 2];
                atomicAdd(&hist[v.x >> 8], 1);
                atomicAdd(&hist[v.y >> 8], 1);
                atomicAdd(&hist[v.z >> 8], 1);
                atomicAdd(&hist[v.w >> 8], 1);
            }
        }
    }
    __syncthreads();
    for (int i = t; i < NBUK; i += 256) histG[i * GE2 + blockIdx.x] = hist[i];
}

// ---- 2-stage scan; chunk-prefix fixup is folded into consumers -------------
__global__ void k_scan1(int* __restrict__ g, int* __restrict__ bsum) {
    __shared__ int s[256];
    int t = threadIdx.x;
    int i4 = blockIdx.x * 256 + t;
    int base = i4 * 4;
    int4 v = make_int4(0, 0, 0, 0);
    if (base + 3 < SCANN) v = ((const int4*)g)[i4];
    else {
        if (base + 0 < SCANN) v.x = g[base + 0];
        if (base + 1 < SCANN) v.y = g[base + 1];
        if (base + 2 < SCANN) v.z = g[base + 2];
        if (base + 3 < SCANN) v.w = g[base + 3];
    }
    int tsum = v.x + v.y + v.z + v.w;
    s[t] = tsum; __syncthreads();
    for (int off = 1; off < 256; off <<= 1) {
        int u = (t >= off) ? s[t - off] : 0;
        __syncthreads();
        s[t] += u;
        __syncthreads();
    }
    int run = s[t] - tsum;
    int4 o;
    o.x = run; run += v.x;
    o.y = run; run += v.y;
    o.z = run; run += v.z;
    o.w = run;
    if (base + 3 < SCANN) ((int4*)g)[i4] = o;
    else {
        if (base + 0 < SCANN) g[base + 0] = o.x;
        if (base + 1 < SCANN) g[base + 1] = o.y;
        if (base + 2 < SCANN) g[base + 2] = o.z;
        if (base + 3 < SCANN) g[base + 3] = o.w;
    }
    if (t == 255) bsum[blockIdx.x] = s[255];
}

__global__ void k_scan2(int* __restrict__ bsum) {
    __shared__ int s[256];
    int t = threadIdx.x;  // 256
    int v = (t < NCH) ? bsum[t] : 0;
    s[t] = v; __syncthreads();
    for (int off = 1; off < 256; off <<= 1) {
        int u = (t >= off) ? s[t - off] : 0;
        __syncthreads();
        s[t] += u;
        __syncthreads();
    }
    if (t < NCH) bsum[t] = s[t] - v;
}

// ---- pass A2: place packed edges, int4-vectorized edge stream --------------
__global__ void k_fillA(const int* __restrict__ ei, const int* __restrict__ histS,
                        const int* __restrict__ bsum, unsigned int* __restrict__ bbuf) {
    __shared__ int cur[NBUK];
    __shared__ int sflag;
    int t = threadIdx.x;  // 256
    for (int i = t; i < NBUK; i += 256) {
        int idx = i * GE2 + blockIdx.x;
        cur[i] = histS[idx] + bsum[idx >> 10];   // fold in chunk prefix
    }
    int f = detect_flag(ei, t, &sflag);   // includes __syncthreads
    int base = blockIdx.x * EBLK;
    if (f) {                               // int64: int4 = 2 edges
        const int4* ps = (const int4*)ei;
        const int4* pd = (const int4*)(ei + 2 * (size_t)NE);
#pragma unroll
        for (int k = 0; k < EBLK / 512; ++k) {
            int e = base + k * 512 + t * 2;
            if (e < NE) {
                int4 vs = ps[e >> 1];
                int4 vd = pd[e >> 1];
                int p0 = atomicAdd(&cur[vd.x >> 8], 1);
                bbuf[p0] = ((unsigned int)(vd.x & 255) << SRCBITS) | (unsigned int)vs.x;
                int p1 = atomicAdd(&cur[vd.z >> 8], 1);
                bbuf[p1] = ((unsigned int)(vd.z & 255) << SRCBITS) | (unsigned int)vs.z;
            }
        }
    } else {                               // int32: int4 = 4 edges
        const int4* ps = (const int4*)ei;
        const int4* pd = (const int4*)(ei + NE);
#pragma unroll
        for (int k = 0; k < EBLK / 1024; ++k) {
            int e = base + k * 1024 + t * 4;
            if (e < NE) {
                int4 vs = ps[e >> 2];
                int4 vd = pd[e >> 2];
                int p0 = atomicAdd(&cur[vd.x >> 8], 1);
                bbuf[p0] = ((unsigned int)(vd.x & 255) << SRCBITS) | (unsigned int)vs.x;
                int p1 = atomicAdd(&cur[vd.y >> 8], 1);
                bbuf[p1] = ((unsigned int)(vd.y & 255) << SRCBITS) | (unsigned int)vs.y;
                int p2 = atomicAdd(&cur[vd.z >> 8], 1);
                bbuf[p2] = ((unsigned int)(vd.z & 255) << SRCBITS) | (unsigned int)vs.z;
                int p3 = atomicAdd(&cur[vd.w >> 8], 1);
                bbuf[p3] = ((unsigned int)(vd.w & 255) << SRCBITS) | (unsigned int)vs.w;
            }
        }
    }
}

// ---- pass B: per-bucket 256-slot sort -> cnt/offs/dinv/xs + csr ------------
__global__ void k_passB(const unsigned int* __restrict__ bbuf, const int* __restrict__ histS,
                        const int* __restrict__ bsum, const float* __restrict__ x,
                        int* __restrict__ cnt, int* __restrict__ offs,
                        float* __restrict__ dinv, float* __restrict__ xs,
                        int* __restrict__ csr) {
    __shared__ int hist[256];
    __shared__ int scn[256];
    __shared__ int cur[256];
    int t = threadIdx.x;  // 256
    int b = blockIdx.x;
    int i0 = b * GE2;
    int base = histS[i0] + bsum[i0 >> 10];
    int next = (b == NBUK - 1) ? NE : (histS[i0 + GE2] + bsum[(i0 + GE2) >> 10]);
    int sz = next - base;
    const unsigned int* buf = bbuf + base;
    hist[t] = 0;
    __syncthreads();
    for (int e = t; e < sz; e += 256)
        atomicAdd(&hist[buf[e] >> SRCBITS], 1);
    __syncthreads();
    int deg = hist[t];
    scn[t] = deg; __syncthreads();
    for (int off = 1; off < 256; off <<= 1) {
        int u = (t >= off) ? scn[t - off] : 0;
        __syncthreads();
        scn[t] += u;
        __syncthreads();
    }
    int myoff = base + scn[t] - deg;
    int node = b * 256 + t;
    if (node < NN) {
        cnt[node]  = deg;
        offs[node] = myoff;
        float d = 1.0f / sqrtf((float)(deg + 1));
        dinv[node] = d;
        float4 xv = ((const float4*)x)[node];
        float4 o; o.x = d * xv.x; o.y = d * xv.y; o.z = d * xv.z; o.w = d * xv.w;
        ((float4*)xs)[node] = o;
    }
    cur[t] = myoff;
    __syncthreads();
    for (int e = t; e < sz; e += 256) {
        unsigned int u = buf[e];
        int p = atomicAdd(&cur[u >> SRCBITS], 1);
        csr[p] = (int)(u & SRCMASK);
    }
}

// ---- fused: layer-1 aggregate (4 thr/node) + h1 + MFMA h1@W2 -> hs ---------
// 64 nodes/block, 256 threads. agg = dinv*(sum_nbr xs[s] + xs[self]).
// mfma_f32_16x16x32_bf16: A[m=lane&15][k=quad*8+j]; D col=lane&15, row=quad*4+reg.
__global__ void k_mm2(const float* __restrict__ xs, const int* __restrict__ cnt,
                      const int* __restrict__ offs, const int* __restrict__ csr,
                      const float* __restrict__ dinv,
                      const float* __restrict__ W1, const float* __restrict__ b1,
                      const float* __restrict__ W2, unsigned short* __restrict__ hs) {
    __shared__ unsigned short h1b[64 * 72];   // [localNode][k], bf16, pad 72
    __shared__ unsigned short w2t[64 * 72];   // [n][k], bf16 (W2 transposed)
    __shared__ float4 sPart[256];             // per-(part,node) partial sums
    __shared__ float4 sAgg[64];
    __shared__ float4 sXs[64];
    __shared__ float sW1[256];
    __shared__ float sb1[64];
    __shared__ float sdv[64];
    __shared__ int scnt[64];
    __shared__ int soff[64];
    int t = threadIdx.x;  // 256
    int base = blockIdx.x * 64;
    if (t < 64) {
        int g = base + t;
        bool ok = (g < NN);
        scnt[t] = ok ? cnt[g] : 0;
        soff[t] = ok ? offs[g] : 0;
        sdv[t]  = ok ? dinv[g] : 0.f;
        sXs[t]  = ok ? ((const float4*)xs)[g] : make_float4(0.f, 0.f, 0.f, 0.f);
        sb1[t]  = b1[t];
    }
    sW1[t] = W1[t];
    for (int i = t; i < 4096; i += 256) {     // W2 [k][n] fp32 -> w2t [n][k] bf16
        int k = i >> 6, n = i & 63;
        w2t[n * 72 + k] = f2bf(W2[i]);
    }
    if (blockIdx.x == 0 && t >= 128 && t < 192) hs[NN * 64 + (t - 128)] = 0;  // sentinel row
    __syncthreads();
    // aggregation: node_l = t&63, part = t>>6 handles j = part, part+4, ...
    {
        int node_l = t & 63, part = t >> 6;
        int n = scnt[node_l], b0 = soff[node_l];
        float4 s = make_float4(0.f, 0.f, 0.f, 0.f);
        int j = part;
        for (; j + 4 < n; j += 8) {           // 2 independent loads in flight
            int s0 = csr[b0 + j], s1 = csr[b0 + j + 4];
            float4 v0 = ((const float4*)xs)[s0];
            float4 v1 = ((const float4*)xs)[s1];
            s.x += v0.x + v1.x; s.y += v0.y + v1.y;
            s.z += v0.z + v1.z; s.w += v0.w + v1.w;
        }
        for (; j < n; j += 4) {
            int s0 = csr[b0 + j];
            float4 v = ((const float4*)xs)[s0];
            s.x += v.x; s.y += v.y; s.z += v.z; s.w += v.w;
        }
        sPart[t] = s;
    }
    __syncthreads();
    if (t < 64) {
        float4 a = sPart[t], b = sPart[t + 64], c = sPart[t + 128], d = sPart[t + 192];
        float4 xi = sXs[t];
        float dn = sdv[t];
        float4 o;
        o.x = dn * (a.x + b.x + c.x + d.x + xi.x);
        o.y = dn * (a.y + b.y + c.y + d.y + xi.y);
        o.z = dn * (a.z + b.z + c.z + d.z + xi.z);
        o.w = dn * (a.w + b.w + c.w + d.w + xi.w);
        sAgg[t] = o;
    }
    __syncthreads();
#pragma unroll
    for (int i = 0; i < 16; ++i) {            // h1 = relu(agg@W1+b1), bf16 to LDS
        int e = i * 256 + t;
        int nl = e >> 6, c = e & 63;
        float4 a = sAgg[nl];
        float h = fmaf(a.x, sW1[c], fmaf(a.y, sW1[64 + c],
                  fmaf(a.z, sW1[128 + c], fmaf(a.w, sW1[192 + c], sb1[c]))));
        h1b[nl * 72 + c] = f2bf(fmaxf(h, 0.f));
    }
    __syncthreads();
    int w = t >> 6, lane = t & 63, l15 = lane & 15, quad = lane >> 4;
    bf16x8 a0 = *(const bf16x8*)&h1b[(w * 16 + l15) * 72 + quad * 8];
    bf16x8 a1 = *(const bf16x8*)&h1b[(w * 16 + l15) * 72 + 32 + quad * 8];
    f32x4 acc[4];
#pragma unroll
    for (int nt = 0; nt < 4; ++nt) {
        bf16x8 bb0 = *(const bf16x8*)&w2t[(nt * 16 + l15) * 72 + quad * 8];
        bf16x8 bb1 = *(const bf16x8*)&w2t[(nt * 16 + l15) * 72 + 32 + quad * 8];
        f32x4 c = {0.f, 0.f, 0.f, 0.f};
        c = __builtin_amdgcn_mfma_f32_16x16x32_bf16(a0, bb0, c, 0, 0, 0);
        c = __builtin_amdgcn_mfma_f32_16x16x32_bf16(a1, bb1, c, 0, 0, 0);
        acc[nt] = c;
    }
#pragma unroll
    for (int nt = 0; nt < 4; ++nt) {
#pragma unroll
        for (int r = 0; r < 4; ++r) {
            int localn = w * 16 + quad * 4 + r;
            int g = base + localn;
            if (g < NN) hs[g * 64 + nt * 16 + l15] = f2bf(acc[nt][r] * sdv[localn]);
        }
    }
}

// ---- layer-2 gather + head, fused, quad-row loads (4 in flight). -----------
// Lane c: group qg=c>>4 takes edges j+qg (mod 4); slot ql=c&15 covers cols
// 4ql..4ql+3 (uint2 = 4 bf16). One wave-load = 4 neighbor rows.
__global__ void k_gather_head(const unsigned short* __restrict__ hs, const int* __restrict__ offs,
                              const int* __restrict__ cnt, const int* __restrict__ csr,
                              const float* __restrict__ dinv, const float* __restrict__ b2,
                              const float* __restrict__ Wl, const float* __restrict__ bl,
                              float* __restrict__ out) {
    int t = threadIdx.x;
    int node = blockIdx.x * 4 + (t >> 6);
    int c = t & 63;
    int qg = c >> 4;
    int ql = c & 15;
    int b = offs[node], n = cnt[node];
    const uint2* hrow = (const uint2*)hs;        // 16 uint2 per row
    int myidx = (c < n) ? csr[b + c] : NN;       // NN = zero sentinel row
    int m = n < 64 ? n : 64;
    float4 A = make_float4(0.f, 0.f, 0.f, 0.f);
    float4 B = make_float4(0.f, 0.f, 0.f, 0.f);
    for (int j = 0; j < m; j += 16) {            // 16 edges per iter, 4 loads in flight
        int s0 = __shfl(myidx, j + qg, 64);
        int s1 = __shfl(myidx, j + 4 + qg, 64);
        int s2 = __shfl(myidx, j + 8 + qg, 64);
        int s3 = __shfl(myidx, j + 12 + qg, 64);
        uint2 u0 = hrow[s0 * 16 + ql];
        uint2 u1 = hrow[s1 * 16 + ql];
        uint2 u2 = hrow[s2 * 16 + ql];
        uint2 u3 = hrow[s3 * 16 + ql];
        A.x += bflo(u0.x); A.y += bfhi(u0.x); A.z += bflo(u0.y); A.w += bfhi(u0.y);
        B.x += bflo(u1.x); B.y += bfhi(u1.x); B.z += bflo(u1.y); B.w += bfhi(u1.y);
        A.x += bflo(u2.x); A.y += bfhi(u2.x); A.z += bflo(u2.y); A.w += bfhi(u2.y);
        B.x += bflo(u3.x); B.y += bfhi(u3.x); B.z += bflo(u3.y); B.w += bfhi(u3.y);
    }
    for (int j = 64; j < n; j += 4) {            // rare: deg > 64
        int e = j + qg;
        int s = (e < n) ? csr[b + e] : NN;
        uint2 u = hrow[s * 16 + ql];
        A.x += bflo(u.x); A.y += bfhi(u.x); A.z += bflo(u.y); A.w += bfhi(u.y);
    }
    float4 S;
    S.x = A.x + B.x; S.y = A.y + B.y; S.z = A.z + B.z; S.w = A.w + B.w;
    S.x += __shfl_xor(S.x, 16, 64); S.x += __shfl_xor(S.x, 32, 64);
    S.y += __shfl_xor(S.y, 16, 64); S.y += __shfl_xor(S.y, 32, 64);
    S.z += __shfl_xor(S.z, 16, 64); S.z += __shfl_xor(S.z, 32, 64);
    S.w += __shfl_xor(S.w, 16, 64); S.w += __shfl_xor(S.w, 32, 64);
    uint2 uS = hrow[node * 16 + ql];             // self loop, once
    S.x += bflo(uS.x); S.y += bfhi(uS.x); S.z += bflo(uS.y); S.w += bfhi(uS.y);
    float4 bv = ((const float4*)b2)[ql];
    float4 wv = ((const float4*)Wl)[ql];
    float dn = dinv[node];
    float v = fmaxf(fmaf(dn, S.x, bv.x), 0.f) * wv.x
            + fmaxf(fmaf(dn, S.y, bv.y), 0.f) * wv.y
            + fmaxf(fmaf(dn, S.z, bv.z), 0.f) * wv.z
            + fmaxf(fmaf(dn, S.w, bv.w), 0.f) * wv.w;
#pragma unroll
    for (int off = 8; off; off >>= 1) v += __shfl_down(v, off, 16);
    if (c == 0) out[node] = v + bl[0];
}

extern "C" void kernel_launch(void* const* d_in, const int* in_sizes, int n_in,
                              void* d_out, int out_size, void* d_ws, size_t ws_size,
                              hipStream_t stream) {
    const float* x  = (const float*)d_in[0];
    const int*   ei = (const int*)d_in[1];
    const float* W1 = (const float*)d_in[2];
    const float* b1 = (const float*)d_in[3];
    const float* W2 = (const float*)d_in[4];
    const float* b2 = (const float*)d_in[5];
    const float* Wl = (const float*)d_in[6];
    const float* bl = (const float*)d_in[7];
    float* out = (float*)d_out;

    char* w = (char*)d_ws;
    float* dinv  = (float*)w;                  w += NN * 4;
    int*   cnt   = (int*)w;                    w += NN * 4;
    int*   offs  = (int*)w;                    w += NN * 4;
    int*   csr   = (int*)w;                    w += NE * 4;
    float* xs    = (float*)w;                  w += NN * 4 * 4;
    unsigned short* hs = (unsigned short*)w;   w += (size_t)(NN + 1) * HID * 2;     // 12.8 MB (+sentinel)
    int*   histG = (int*)w;                    w += (size_t)((SCANN + 3) & ~3) * 4; // 612 KB
    int*   bsum  = (int*)w;                    w += 256 * 4;
    unsigned int* bbuf = (unsigned int*)w;     w += (size_t)NE * 4;                 // 6.4 MB

    const int GMM = (NN + 63) / 64;        // 1563

    hipLaunchKernelGGL(k_histA,  dim3(GE2),  dim3(256), 0, stream, ei, histG);
    hipLaunchKernelGGL(k_scan1,  dim3(NCH),  dim3(256), 0, stream, histG, bsum);
    hipLaunchKernelGGL(k_scan2,  dim3(1),    dim3(256), 0, stream, bsum);
    hipLaunchKernelGGL(k_fillA,  dim3(GE2),  dim3(256), 0, stream, ei, histG, bsum, bbuf);
    hipLaunchKernelGGL(k_passB,  dim3(NBUK), dim3(256), 0, stream,
                       bbuf, histG, bsum, x, cnt, offs, dinv, xs, csr);
    hipLaunchKernelGGL(k_mm2, dim3(GMM), dim3(256), 0, stream,
                       xs, cnt, offs, csr, dinv, W1, b1, W2, hs);
    hipLaunchKernelGGL(k_gather_head, dim3(NN / 4), dim3(256), 0, stream,
                       hs, offs, cnt, csr, dinv, b2, Wl, bl, out);
}